// Round 8
// baseline (2414.085 us; speedup 1.0000x reference)
//
#include <hip/hip_runtime.h>

using f4_t  = __attribute__((ext_vector_type(4))) float;
using bf8_t = __attribute__((ext_vector_type(8))) short;
using u32x4 = __attribute__((ext_vector_type(4))) unsigned int;

#define T_DIM 512
#define B_DIM 256
#define I_DIM 256
#define H_DIM 1024
#define O_DIM 128

// XOR swizzle: spread 16B slots of a row across banks (T2 recipe)
#define SWZ(row, byte) ((byte) ^ (((row) & 7) << 4))

#define SMASK 0x8000800080008000ull  // bf16 sign bits of a 4-element qword

__device__ __forceinline__ unsigned short f2bf(float f) {
  unsigned u = __builtin_bit_cast(unsigned, f);
  return (unsigned short)((u + 0x7FFFu + ((u >> 16) & 1u)) >> 16);
}

__device__ __forceinline__ unsigned long long pack4bf(f4_t v) {
  unsigned long long r;
  r  = (unsigned long long)f2bf(v[0]);
  r |= (unsigned long long)f2bf(v[1]) << 16;
  r |= (unsigned long long)f2bf(v[2]) << 32;
  r |= (unsigned long long)f2bf(v[3]) << 48;
  return r;
}

// ---------------------------------------------------------------- init ------
// hbuf1 = initial h (zeros) tagged phase-1 (0x8000 = -0.0 bf16).  hbuf0 needs
// no init (tags reject all stale content).  done flags zeroed every launch.
__global__ __launch_bounds__(256, 1) void k_init(
    const float* __restrict__ Wi, const float* __restrict__ Wh,
    const float* __restrict__ Wo, unsigned short* __restrict__ Wi_b,
    unsigned short* __restrict__ Wh_b, unsigned short* __restrict__ Wo_b,
    unsigned short* __restrict__ hbuf1, unsigned* __restrict__ done) {
  int idx = blockIdx.x * 256 + threadIdx.x;
  int stride = gridDim.x * 256;
  for (int i = idx; i < H_DIM * H_DIM; i += stride) Wh_b[i] = f2bf(Wh[i]);
  for (int i = idx; i < H_DIM * I_DIM; i += stride) Wi_b[i] = f2bf(Wi[i]);
  for (int i = idx; i < O_DIM * H_DIM; i += stride) Wo_b[i] = f2bf(Wo[i]);
  for (int i = idx; i < B_DIM * H_DIM; i += stride) hbuf1[i] = 0x8000;
  for (int i = idx; i < 256 * 32; i += stride) done[i] = 0;
}

// --------------------------------------------------- phase 1: x @ Wi^T + bi -
__global__ __launch_bounds__(256, 2) void k_inproj(
    const float* __restrict__ x, const unsigned short* __restrict__ Wi_b,
    const float* __restrict__ bi, float* __restrict__ act) {
  __shared__ unsigned short As[128 * 128];
  __shared__ unsigned short Bs[128 * 128];
  int blk = blockIdx.x;
  int mb = (blk & 7) * 128 + (blk >> 6);
  int nb = (blk >> 3) & 7;
  int m0 = mb * 128, n0 = nb * 128;
  int tid = threadIdx.x;
  int lane = tid & 63, w = tid >> 6;
  int wm0 = (w & 1) * 64, wn0 = (w >> 1) * 64;
  int lrow = lane & 15, lk = (lane >> 4) * 8;
  f4_t acc[4][4];
#pragma unroll
  for (int a = 0; a < 4; ++a)
#pragma unroll
    for (int b = 0; b < 4; ++b) acc[a][b] = (f4_t){0.f, 0.f, 0.f, 0.f};

  for (int kb = 0; kb < 2; ++kb) {
    if (kb) __syncthreads();
#pragma unroll
    for (int it = 0; it < 16; ++it) {
      int c = it * 256 + tid;
      int row = c >> 5;
      int kc = (c & 31) * 4;
      f4_t v = *(const f4_t*)(x + (size_t)(m0 + row) * I_DIM + kb * 128 + kc);
      *(unsigned long long*)((char*)As + SWZ(row, row * 256 + kc * 2)) = pack4bf(v);
    }
#pragma unroll
    for (int it = 0; it < 8; ++it) {
      int c = it * 256 + tid;
      int row = c >> 4;
      int k16 = c & 15;
      u32x4 v = *(const u32x4*)(Wi_b + (size_t)(n0 + row) * I_DIM + kb * 128 + k16 * 8);
      *(u32x4*)((char*)Bs + SWZ(row, row * 256 + k16 * 16)) = v;
    }
    __syncthreads();
#pragma unroll
    for (int ks = 0; ks < 4; ++ks) {
      bf8_t aF[4], bF[4];
#pragma unroll
      for (int mt = 0; mt < 4; ++mt) {
        int row = wm0 + mt * 16 + lrow;
        aF[mt] = *(const bf8_t*)((char*)As + SWZ(row, row * 256 + (ks * 32 + lk) * 2));
      }
#pragma unroll
      for (int nt = 0; nt < 4; ++nt) {
        int row = wn0 + nt * 16 + lrow;
        bF[nt] = *(const bf8_t*)((char*)Bs + SWZ(row, row * 256 + (ks * 32 + lk) * 2));
      }
#pragma unroll
      for (int mt = 0; mt < 4; ++mt)
#pragma unroll
        for (int nt = 0; nt < 4; ++nt)
          acc[mt][nt] =
              __builtin_amdgcn_mfma_f32_16x16x32_bf16(aF[mt], bF[nt], acc[mt][nt], 0, 0, 0);
    }
  }
#pragma unroll
  for (int nt = 0; nt < 4; ++nt) {
    int col = n0 + wn0 + nt * 16 + lrow;
    float bv = bi[col];
#pragma unroll
    for (int mt = 0; mt < 4; ++mt) {
      int rbase = m0 + wm0 + mt * 16 + (lane >> 4) * 4;
#pragma unroll
      for (int r = 0; r < 4; ++r)
        act[(size_t)(rbase + r) * H_DIM + col] = acc[mt][nt][r] + bv;
    }
  }
}

// ------------------------------------------------------- phase 2: the scan --
// R8 = R7 skeleton + jitter surgery:
//  - u-reads BATCHED 4 steps deep into registers (issued off-path after the
//    flag, consumed via explicit selects -- rule 20).  Removes the per-step
//    16B HBM-miss (900-1500cy, high variance) whose tail was amplified by the
//    max-over-16 producer coupling.
//  - detect poll: two outstanding loads, no s_sleep -> ~half the quantization.
//  - otherwise identical to R7 (hint flags + sign-bit tag validation).
__global__ __launch_bounds__(256, 1) void k_scan(
    const unsigned short* __restrict__ Wh_b, const float* __restrict__ bh,
    float* __restrict__ act, unsigned short* __restrict__ hbuf0,
    unsigned short* __restrict__ hbuf1, unsigned* __restrict__ done) {
  __shared__ __align__(16) float pbuf[4][16][68];  // 68: 2-way bank alias (free)
  int blk = blockIdx.x;
  int g = blk & 15, hs = blk >> 4;
  int b0 = g * 16, h0 = hs * 64;
  int tid = threadIdx.x;
  int lane = tid & 63, w = tid >> 6;
  int lrow = lane & 15, lgq = lane >> 4, lk = lgq * 8;

  // persistent Wh fragments: [n-tile][k-chunk], K-slice = w*256..w*256+255
  bf8_t Bf[4][8];
#pragma unroll
  for (int n = 0; n < 4; ++n)
#pragma unroll
    for (int kc = 0; kc < 8; ++kc)
      Bf[n][kc] = *(const bf8_t*)(Wh_b + (size_t)(h0 + n * 16 + lrow) * H_DIM +
                                  w * 256 + kc * 32 + lk);

  int pr = tid >> 4, pc = (tid & 15) * 4;  // pointwise ownership
  float st[4] = {0.f, 0.f, 0.f, 0.f};
  f4_t bh4 = *(const f4_t*)(bh + h0 + pc);

  unsigned short* hb[2] = {hbuf0, hbuf1};
  unsigned* myslot = done + (g * 16 + hs) * 32;
  const unsigned* pollp = done + (g * 16 + 4 * w + (lane & 3)) * 32;
  bool dopoll = (lane < 4) && (4 * w + lane != hs);  // skip own slot

  const float* uarow = act + (size_t)(b0 + pr) * H_DIM + h0 + pc;

  // initial u batch: steps 0..3 (T_DIM % 4 == 0)
  f4_t ub0, ub1, ub2, ub3;
  ub0 = *(const f4_t*)(uarow + (size_t)0 * B_DIM * H_DIM);
  ub1 = *(const f4_t*)(uarow + (size_t)1 * B_DIM * H_DIM);
  ub2 = *(const f4_t*)(uarow + (size_t)2 * B_DIM * H_DIM);
  ub3 = *(const f4_t*)(uarow + (size_t)3 * B_DIM * H_DIM);

  for (int t = 0; t < T_DIM; ++t) {
    int p = t & 1;
    const unsigned short* hprev = hb[p ^ 1];
    unsigned long long want = (((unsigned)(t - 1) >> 1) & 1u) ? SMASK : 0ull;

    // ---- cheap detect: wave w polls its 4 producers' 4B flags (2 in flight)
    if (t > 0 && dopoll) {
      int gd = 0;
      for (;;) {
        unsigned a = __hip_atomic_load(pollp, __ATOMIC_RELAXED, __HIP_MEMORY_SCOPE_AGENT);
        unsigned b = __hip_atomic_load(pollp, __ATOMIC_RELAXED, __HIP_MEMORY_SCOPE_AGENT);
        if (a >= (unsigned)t || b >= (unsigned)t || ++gd >= 60000) break;
      }
    }
    __builtin_amdgcn_sched_barrier(0);  // keep data loads below the detect

    // ---- fetch once: batched 16x8B agent loads of this lane's fragment rows
    const unsigned long long* ap =
        (const unsigned long long*)hprev + (size_t)(b0 + lrow) * 256 + (size_t)w * 64;
    unsigned long long q[16];
#pragma unroll
    for (int kc = 0; kc < 8; ++kc) {
      q[2 * kc] = __hip_atomic_load(ap + kc * 8 + 2 * lgq, __ATOMIC_RELAXED,
                                    __HIP_MEMORY_SCOPE_AGENT);
      q[2 * kc + 1] = __hip_atomic_load(ap + kc * 8 + 2 * lgq + 1, __ATOMIC_RELAXED,
                                        __HIP_MEMORY_SCOPE_AGENT);
    }

    // ---- validate tags (flag was a hint); re-read only on the rare race
    int vg = 0;
    for (;;) {
      unsigned long long bad = 0;
#pragma unroll
      for (int i = 0; i < 16; ++i) bad |= (q[i] ^ want) & SMASK;
      if (!__any(bad != 0)) break;
      if (++vg >= 3000) break;
      __builtin_amdgcn_s_sleep(1);
#pragma unroll
      for (int kc = 0; kc < 8; ++kc) {
        q[2 * kc] = __hip_atomic_load(ap + kc * 8 + 2 * lgq, __ATOMIC_RELAXED,
                                      __HIP_MEMORY_SCOPE_AGENT);
        q[2 * kc + 1] = __hip_atomic_load(ap + kc * 8 + 2 * lgq + 1, __ATOMIC_RELAXED,
                                          __HIP_MEMORY_SCOPE_AGENT);
      }
    }
    if (want) {
#pragma unroll
      for (int i = 0; i < 16; ++i) q[i] &= ~SMASK;  // strip tags (-0 -> +0)
    }
    bf8_t Af[8];
#pragma unroll
    for (int kc = 0; kc < 8; ++kc) {
      union { unsigned long long qq[2]; bf8_t v; } uu;
      uu.qq[0] = q[2 * kc];
      uu.qq[1] = q[2 * kc + 1];
      Af[kc] = uu.v;
    }

    // ---- MFMA partials (4 independent accumulator chains)
    f4_t acc[4];
#pragma unroll
    for (int n = 0; n < 4; ++n) acc[n] = (f4_t){0.f, 0.f, 0.f, 0.f};
#pragma unroll
    for (int kc = 0; kc < 8; ++kc)
#pragma unroll
      for (int n = 0; n < 4; ++n)
        acc[n] = __builtin_amdgcn_mfma_f32_16x16x32_bf16(Af[kc], Bf[n][kc], acc[n], 0, 0, 0);

    // ---- cross-wave K reduction (lgkm-only barrier; no vmcnt drain)
#pragma unroll
    for (int n = 0; n < 4; ++n)
#pragma unroll
      for (int r = 0; r < 4; ++r)
        pbuf[w][lgq * 4 + r][n * 16 + lrow] = acc[n][r];
    asm volatile("s_waitcnt lgkmcnt(0)\ns_barrier" ::: "memory");
    __builtin_amdgcn_sched_barrier(0);  // rule 18: keep ds_reads below

    // ---- pointwise: vectorized partial-sum + leaky update + relu
    int sel = t & 3;
    f4_t ucur = (sel == 0) ? ub0 : (sel == 1) ? ub1 : (sel == 2) ? ub2 : ub3;
    f4_t s0 = *(const f4_t*)&pbuf[0][pr][pc];
    f4_t s1 = *(const f4_t*)&pbuf[1][pr][pc];
    f4_t s2 = *(const f4_t*)&pbuf[2][pr][pc];
    f4_t s3 = *(const f4_t*)&pbuf[3][pr][pc];
    f4_t tot = s0 + s1 + s2 + s3 + ucur + bh4;
    f4_t hres;
#pragma unroll
    for (int j = 0; j < 4; ++j) {
      st[j] = st[j] * 0.8f + tot[j] * 0.2f;
      hres[j] = fmaxf(st[j], 0.f);
    }

    // ---- tagged h store (fire-and-forget; tags make it self-validating)
    unsigned long long hp = pack4bf(hres) | (((t >> 1) & 1) ? SMASK : 0ull);
    __hip_atomic_store(
        (unsigned long long*)(hb[p] + (size_t)(b0 + pr) * H_DIM + h0 + pc), hp,
        __ATOMIC_RELAXED, __HIP_MEMORY_SCOPE_AGENT);

    // bare barrier: all threads ISSUED their stores (no ack wait)
    asm volatile("s_barrier" ::: "memory");
    if (tid == 0)
      __hip_atomic_store(myslot, (unsigned)(t + 1), __ATOMIC_RELAXED,
                         __HIP_MEMORY_SCOPE_AGENT);  // hint flag

    // ---- off-path: refill u batch every 4th step (same-thread slots only;
    // acts[t+1..t+4] are written by this thread at steps t+1..t+4, after
    // these loads issue -> no conflict), then act store.
    if ((t & 3) == 3 && t + 1 < T_DIM) {
      ub0 = *(const f4_t*)(uarow + (size_t)(t + 1) * B_DIM * H_DIM);
      ub1 = *(const f4_t*)(uarow + (size_t)(t + 2) * B_DIM * H_DIM);
      ub2 = *(const f4_t*)(uarow + (size_t)(t + 3) * B_DIM * H_DIM);
      ub3 = *(const f4_t*)(uarow + (size_t)(t + 4) * B_DIM * H_DIM);
    }
    *(f4_t*)(act + ((size_t)t * B_DIM + b0 + pr) * H_DIM + h0 + pc) = hres;
  }
}

// ------------------------------------------------- phase 3: act @ Wo^T + bo -
__global__ __launch_bounds__(256, 2) void k_outproj(
    const float* __restrict__ act, const unsigned short* __restrict__ Wo_b,
    const float* __restrict__ bo, float* __restrict__ out) {
  __shared__ unsigned short As[128 * 64];
  __shared__ unsigned short Bs[128 * 64];
  int m0 = blockIdx.x * 128;
  int tid = threadIdx.x;
  int lane = tid & 63, w = tid >> 6;
  int wm0 = (w & 1) * 64, wn0 = (w >> 1) * 64;
  int lrow = lane & 15, lk = (lane >> 4) * 8;
  f4_t acc[4][4];
#pragma unroll
  for (int a = 0; a < 4; ++a)
#pragma unroll
    for (int b = 0; b < 4; ++b) acc[a][b] = (f4_t){0.f, 0.f, 0.f, 0.f};

  for (int kb = 0; kb < 16; ++kb) {
    if (kb) __syncthreads();
#pragma unroll
    for (int it = 0; it < 8; ++it) {
      int c = it * 256 + tid;
      int row = c >> 4;
      int kc = (c & 15) * 4;
      f4_t v = *(const f4_t*)(act + (size_t)(m0 + row) * H_DIM + kb * 64 + kc);
      *(unsigned long long*)((char*)As + SWZ(row, row * 128 + kc * 2)) = pack4bf(v);
    }
#pragma unroll
    for (int it = 0; it < 4; ++it) {
      int c = it * 256 + tid;
      int row = c >> 3;
      int k16 = c & 7;
      u32x4 v = *(const u32x4*)(Wo_b + (size_t)row * H_DIM + kb * 64 + k16 * 8);
      *(u32x4*)((char*)Bs + SWZ(row, row * 128 + k16 * 16)) = v;
    }
    __syncthreads();
#pragma unroll
    for (int ks = 0; ks < 2; ++ks) {
      bf8_t aF[4], bF[4];
#pragma unroll
      for (int mt = 0; mt < 4; ++mt) {
        int row = wm0 + mt * 16 + lrow;
        aF[mt] = *(const bf8_t*)((char*)As + SWZ(row, row * 128 + (ks * 32 + lk) * 2));
      }
#pragma unroll
      for (int nt = 0; nt < 4; ++nt) {
        int row = wn0 + nt * 16 + lrow;
        bF[nt] = *(const bf8_t*)((char*)Bs + SWZ(row, row * 128 + (ks * 32 + lk) * 2));
      }
#pragma unroll
      for (int mt = 0; mt < 4; ++mt)
#pragma unroll
        for (int nt = 0; nt < 4; ++nt)
          acc[mt][nt] =
              __builtin_amdgcn_mfma_f32_16x16x32_bf16(aF[mt], bF[nt], acc[mt][nt], 0, 0, 0);
    }
  }
#pragma unroll
  for (int nt = 0; nt < 4; ++nt) {
    int col = wn0 + nt * 16 + lrow;
    float bv = bo[col];
#pragma unroll
    for (int mt = 0; mt < 4; ++mt) {
      int rbase = m0 + wm0 + mt * 16 + (lane >> 4) * 4;
#pragma unroll
      for (int r = 0; r < 4; ++r)
        out[(size_t)(rbase + r) * O_DIM + col] = acc[mt][nt][r] + bv;
    }
  }
}

// ---------------------------------------------------------------------------
extern "C" void kernel_launch(void* const* d_in, const int* in_sizes, int n_in,
                              void* d_out, int out_size, void* d_ws, size_t ws_size,
                              hipStream_t stream) {
  const float* x  = (const float*)d_in[0];
  const float* Wi = (const float*)d_in[1];
  const float* bi = (const float*)d_in[2];
  const float* Wh = (const float*)d_in[3];
  const float* bh = (const float*)d_in[4];
  const float* Wo = (const float*)d_in[5];
  const float* bo = (const float*)d_in[6];

  float* out = (float*)d_out;                                  // [T,B,O]
  float* act = out + (size_t)T_DIM * B_DIM * O_DIM;            // [T,B,H]

  char* ws = (char*)d_ws;
  unsigned short* Wh_b  = (unsigned short*)(ws);                               // 2 MB
  unsigned short* Wi_b  = (unsigned short*)(ws + (2u << 20));                  // 512 KB
  unsigned short* Wo_b  = (unsigned short*)(ws + (2u << 20) + (512u << 10));   // 256 KB
  unsigned short* hbuf0 = (unsigned short*)(ws + (2u << 20) + (768u << 10));   // 512 KB
  unsigned short* hbuf1 = (unsigned short*)(ws + (2u << 20) + (1280u << 10));  // 512 KB
  unsigned* done        = (unsigned*)(ws + (2u << 20) + (1792u << 10));        // 32 KB

  k_init<<<1024, 256, 0, stream>>>(Wi, Wh, Wo, Wi_b, Wh_b, Wo_b, hbuf1, done);
  k_inproj<<<8192, 256, 0, stream>>>(x, Wi_b, bi, act);
  k_scan<<<256, 256, 0, stream>>>(Wh_b, bh, act, hbuf0, hbuf1, done);
  k_outproj<<<1024, 256, 0, stream>>>(act, Wo_b, bo, out);
}

// Round 9
// 1612.097 us; speedup vs baseline: 1.4975x; 1.4975x over previous
//
#include <hip/hip_runtime.h>

using f4_t  = __attribute__((ext_vector_type(4))) float;
using bf8_t = __attribute__((ext_vector_type(8))) short;
using u32x4 = __attribute__((ext_vector_type(4))) unsigned int;

#define T_DIM 512
#define B_DIM 256
#define I_DIM 256
#define H_DIM 1024
#define O_DIM 128

// XOR swizzle: spread 16B slots of a row across banks (T2 recipe)
#define SWZ(row, byte) ((byte) ^ (((row) & 7) << 4))

#define SMASK 0x8000800080008000ull  // bf16 sign bits of a 4-element qword

__device__ __forceinline__ unsigned short f2bf(float f) {
  unsigned u = __builtin_bit_cast(unsigned, f);
  return (unsigned short)((u + 0x7FFFu + ((u >> 16) & 1u)) >> 16);
}

__device__ __forceinline__ unsigned long long pack4bf(f4_t v) {
  unsigned long long r;
  r  = (unsigned long long)f2bf(v[0]);
  r |= (unsigned long long)f2bf(v[1]) << 16;
  r |= (unsigned long long)f2bf(v[2]) << 32;
  r |= (unsigned long long)f2bf(v[3]) << 48;
  return r;
}

// ---------------------------------------------------------------- init ------
__global__ __launch_bounds__(256, 1) void k_init(
    const float* __restrict__ Wi, const float* __restrict__ Wh,
    const float* __restrict__ Wo, unsigned short* __restrict__ Wi_b,
    unsigned short* __restrict__ Wh_b, unsigned short* __restrict__ Wo_b,
    unsigned short* __restrict__ hbuf1, unsigned* __restrict__ done) {
  int idx = blockIdx.x * 256 + threadIdx.x;
  int stride = gridDim.x * 256;
  for (int i = idx; i < H_DIM * H_DIM; i += stride) Wh_b[i] = f2bf(Wh[i]);
  for (int i = idx; i < H_DIM * I_DIM; i += stride) Wi_b[i] = f2bf(Wi[i]);
  for (int i = idx; i < O_DIM * H_DIM; i += stride) Wo_b[i] = f2bf(Wo[i]);
  for (int i = idx; i < B_DIM * H_DIM; i += stride) hbuf1[i] = 0x8000;
  for (int i = idx; i < 256 * 32; i += stride) done[i] = 0;
}

// --------------------------------------------------- phase 1: x @ Wi^T + bi -
__global__ __launch_bounds__(256, 2) void k_inproj(
    const float* __restrict__ x, const unsigned short* __restrict__ Wi_b,
    const float* __restrict__ bi, float* __restrict__ act) {
  __shared__ unsigned short As[128 * 128];
  __shared__ unsigned short Bs[128 * 128];
  int blk = blockIdx.x;
  int mb = (blk & 7) * 128 + (blk >> 6);
  int nb = (blk >> 3) & 7;
  int m0 = mb * 128, n0 = nb * 128;
  int tid = threadIdx.x;
  int lane = tid & 63, w = tid >> 6;
  int wm0 = (w & 1) * 64, wn0 = (w >> 1) * 64;
  int lrow = lane & 15, lk = (lane >> 4) * 8;
  f4_t acc[4][4];
#pragma unroll
  for (int a = 0; a < 4; ++a)
#pragma unroll
    for (int b = 0; b < 4; ++b) acc[a][b] = (f4_t){0.f, 0.f, 0.f, 0.f};

  for (int kb = 0; kb < 2; ++kb) {
    if (kb) __syncthreads();
#pragma unroll
    for (int it = 0; it < 16; ++it) {
      int c = it * 256 + tid;
      int row = c >> 5;
      int kc = (c & 31) * 4;
      f4_t v = *(const f4_t*)(x + (size_t)(m0 + row) * I_DIM + kb * 128 + kc);
      *(unsigned long long*)((char*)As + SWZ(row, row * 256 + kc * 2)) = pack4bf(v);
    }
#pragma unroll
    for (int it = 0; it < 8; ++it) {
      int c = it * 256 + tid;
      int row = c >> 4;
      int k16 = c & 15;
      u32x4 v = *(const u32x4*)(Wi_b + (size_t)(n0 + row) * I_DIM + kb * 128 + k16 * 8);
      *(u32x4*)((char*)Bs + SWZ(row, row * 256 + k16 * 16)) = v;
    }
    __syncthreads();
#pragma unroll
    for (int ks = 0; ks < 4; ++ks) {
      bf8_t aF[4], bF[4];
#pragma unroll
      for (int mt = 0; mt < 4; ++mt) {
        int row = wm0 + mt * 16 + lrow;
        aF[mt] = *(const bf8_t*)((char*)As + SWZ(row, row * 256 + (ks * 32 + lk) * 2));
      }
#pragma unroll
      for (int nt = 0; nt < 4; ++nt) {
        int row = wn0 + nt * 16 + lrow;
        bF[nt] = *(const bf8_t*)((char*)Bs + SWZ(row, row * 256 + (ks * 32 + lk) * 2));
      }
#pragma unroll
      for (int mt = 0; mt < 4; ++mt)
#pragma unroll
        for (int nt = 0; nt < 4; ++nt)
          acc[mt][nt] =
              __builtin_amdgcn_mfma_f32_16x16x32_bf16(aF[mt], bF[nt], acc[mt][nt], 0, 0, 0);
    }
  }
#pragma unroll
  for (int nt = 0; nt < 4; ++nt) {
    int col = n0 + wn0 + nt * 16 + lrow;
    float bv = bi[col];
#pragma unroll
    for (int mt = 0; mt < 4; ++mt) {
      int rbase = m0 + wm0 + mt * 16 + (lane >> 4) * 4;
#pragma unroll
      for (int r = 0; r < 4; ++r)
        act[(size_t)(rbase + r) * H_DIM + col] = acc[mt][nt][r] + bv;
    }
  }
}

// ------------------------------------------------------- phase 2: the scan --
// R9: TRANSACTION-COUNT surgery.  The h-exchange was 4096 independent 8B
// agent-atomic txns per WG per step (they never coalesce) -- the invariant
// ~1950us across R3/R7/R8 is txn-throughput, not latency legs.  Now:
//  - flags gate entry (R7-proven); per-element sign-bit tags remain the
//    correctness mechanism (8B atomicity never needed).
//  - bulk fetch: 8 batched WAVE-CONTIGUOUS 16B loads/thread with sc0 sc1
//    (same cache-bypass policy the compiler emits for agent atomics, but
//    coalescable: 64B-line-perfect, ~512 line-txns/WG vs 4096).
//  - per-thread tag validation with bounded independent retry (no wave
//    coupling), sign-strip, then LDS redistribute (swizzled) to fragments.
__global__ __launch_bounds__(256, 1) void k_scan(
    const unsigned short* __restrict__ Wh_b, const float* __restrict__ bh,
    float* __restrict__ act, unsigned short* __restrict__ hbuf0,
    unsigned short* __restrict__ hbuf1, unsigned* __restrict__ done) {
  __shared__ __align__(16) char hT[16 * 2048];     // staged h(t-1): 16 rows x 1024 col
  __shared__ __align__(16) float pbuf[4][16][68];  // K-partials (68: 2-way alias, free)
  int blk = blockIdx.x;
  int g = blk & 15, hs = blk >> 4;
  int b0 = g * 16, h0 = hs * 64;
  int tid = threadIdx.x;
  int lane = tid & 63, w = tid >> 6;
  int lrow = lane & 15, lgq = lane >> 4, lk = lgq * 8;

  // persistent Wh fragments: [n-tile][k-chunk], K-slice = w*256..w*256+255
  bf8_t Bf[4][8];
#pragma unroll
  for (int n = 0; n < 4; ++n)
#pragma unroll
    for (int kc = 0; kc < 8; ++kc)
      Bf[n][kc] = *(const bf8_t*)(Wh_b + (size_t)(h0 + n * 16 + lrow) * H_DIM +
                                  w * 256 + kc * 32 + lk);

  int pr = tid >> 4, pc = (tid & 15) * 4;  // pointwise ownership
  float st[4] = {0.f, 0.f, 0.f, 0.f};
  f4_t bh4 = *(const f4_t*)(bh + h0 + pc);

  unsigned short* hb[2] = {hbuf0, hbuf1};
  unsigned* myslot = done + (g * 16 + hs) * 32;
  const unsigned* pollp = done + (g * 16 + (lane & 15)) * 32;
  bool dopoll = (lane < 16) && (lane != hs);  // each wave gates on all 16 producers

  int rh = tid >> 7;            // staging: row parity within a 4KB sweep
  int colb = (tid & 127) * 16;  // staging: byte col within row

  // prefetch u for t=0
  f4_t ucur = *(const f4_t*)(act + (size_t)(b0 + pr) * H_DIM + h0 + pc);

  for (int t = 0; t < T_DIM; ++t) {
    int p = t & 1;
    const unsigned short* hprev = hb[p ^ 1];
    unsigned wtag = ((unsigned)(t - 1) >> 1) & 1u;  // t=0 -> 1 (matches init)
    unsigned want32 = wtag ? 0x80008000u : 0u;

    // ---- detect: lanes 0..15 of every wave poll the 16 producer flags
    if (t > 0 && dopoll) {
      int gd = 0;
      while (__hip_atomic_load(pollp, __ATOMIC_RELAXED, __HIP_MEMORY_SCOPE_AGENT) <
                 (unsigned)t &&
             ++gd < 60000)
        __builtin_amdgcn_s_sleep(1);
    }
    __builtin_amdgcn_sched_barrier(0);

    // ---- fetch: 8 coalesced 16B sc0,sc1 loads (128B/thread, one batch wait)
    const char* base = (const char*)(hprev + (size_t)b0 * H_DIM);
    unsigned long long a0 = (unsigned long long)(base + tid * 16);
    u32x4 q0, q1, q2, q3, q4, q5, q6, q7;
    asm volatile(
        "global_load_dwordx4 %[d0], %[a0], off sc0 sc1\n\t"
        "global_load_dwordx4 %[d1], %[a1], off sc0 sc1\n\t"
        "global_load_dwordx4 %[d2], %[a2], off sc0 sc1\n\t"
        "global_load_dwordx4 %[d3], %[a3], off sc0 sc1\n\t"
        "global_load_dwordx4 %[d4], %[a4], off sc0 sc1\n\t"
        "global_load_dwordx4 %[d5], %[a5], off sc0 sc1\n\t"
        "global_load_dwordx4 %[d6], %[a6], off sc0 sc1\n\t"
        "global_load_dwordx4 %[d7], %[a7], off sc0 sc1\n\t"
        "s_waitcnt vmcnt(0)"
        : [d0] "=&v"(q0), [d1] "=&v"(q1), [d2] "=&v"(q2), [d3] "=&v"(q3),
          [d4] "=&v"(q4), [d5] "=&v"(q5), [d6] "=&v"(q6), [d7] "=&v"(q7)
        : [a0] "v"(a0), [a1] "v"(a0 + 4096), [a2] "v"(a0 + 8192),
          [a3] "v"(a0 + 12288), [a4] "v"(a0 + 16384), [a5] "v"(a0 + 20480),
          [a6] "v"(a0 + 24576), [a7] "v"(a0 + 28672)
        : "memory");
    __builtin_amdgcn_sched_barrier(0);

    // prefetch next step's u while validation runs
    int tn = (t + 1 < T_DIM) ? t + 1 : t;
    f4_t unext = *(const f4_t*)(act + ((size_t)tn * B_DIM + b0 + pr) * H_DIM + h0 + pc);

    // ---- per-thread tag validation; independent bounded retry of stale 16B
#define STALE(qq) \
  ((((qq[0] ^ want32) | (qq[1] ^ want32) | (qq[2] ^ want32) | (qq[3] ^ want32)) & \
    0x80008000u) != 0u)
#define RELOAD(qq, ad)                                                          \
  asm volatile("global_load_dwordx4 %0, %1, off sc0 sc1\n\ts_waitcnt vmcnt(0)"  \
               : "=&v"(qq)                                                      \
               : "v"(ad)                                                        \
               : "memory")
    {
      int vg = 0;
      for (;;) {
        unsigned m = (STALE(q0) ? 1u : 0u) | (STALE(q1) ? 2u : 0u) |
                     (STALE(q2) ? 4u : 0u) | (STALE(q3) ? 8u : 0u) |
                     (STALE(q4) ? 16u : 0u) | (STALE(q5) ? 32u : 0u) |
                     (STALE(q6) ? 64u : 0u) | (STALE(q7) ? 128u : 0u);
        if (m == 0u || ++vg >= 400) break;
        __builtin_amdgcn_s_sleep(1);
        if (m & 1u) RELOAD(q0, a0);
        if (m & 2u) RELOAD(q1, a0 + 4096);
        if (m & 4u) RELOAD(q2, a0 + 8192);
        if (m & 8u) RELOAD(q3, a0 + 12288);
        if (m & 16u) RELOAD(q4, a0 + 16384);
        if (m & 32u) RELOAD(q5, a0 + 20480);
        if (m & 64u) RELOAD(q6, a0 + 24576);
        if (m & 128u) RELOAD(q7, a0 + 28672);
      }
    }
#undef STALE
#undef RELOAD
    // strip tags (values >= 0, sign bit is pure tag)
#pragma unroll
    for (int d = 0; d < 4; ++d) {
      q0[d] &= 0x7fff7fffu; q1[d] &= 0x7fff7fffu; q2[d] &= 0x7fff7fffu;
      q3[d] &= 0x7fff7fffu; q4[d] &= 0x7fff7fffu; q5[d] &= 0x7fff7fffu;
      q6[d] &= 0x7fff7fffu; q7[d] &= 0x7fff7fffu;
    }

    // ---- redistribute: swizzled LDS staging (write contiguous, SWZ per row)
#define STAGE(qq, r)                                                            \
  *(u32x4*)(&hT[(2 * (r) + rh) * 2048 + SWZ(2 * (r) + rh, colb)]) = qq
    STAGE(q0, 0); STAGE(q1, 1); STAGE(q2, 2); STAGE(q3, 3);
    STAGE(q4, 4); STAGE(q5, 5); STAGE(q6, 6); STAGE(q7, 7);
#undef STAGE
    asm volatile("s_waitcnt lgkmcnt(0)\ns_barrier" ::: "memory");
    __builtin_amdgcn_sched_barrier(0);

    // ---- fragments from LDS + MFMA partials over this wave's K-slice
    f4_t acc[4];
#pragma unroll
    for (int n = 0; n < 4; ++n) acc[n] = (f4_t){0.f, 0.f, 0.f, 0.f};
#pragma unroll
    for (int kc = 0; kc < 8; ++kc) {
      int cbyte = w * 512 + kc * 64 + lgq * 16;
      bf8_t Af = *(const bf8_t*)(&hT[lrow * 2048 + SWZ(lrow, cbyte)]);
#pragma unroll
      for (int n = 0; n < 4; ++n)
        acc[n] = __builtin_amdgcn_mfma_f32_16x16x32_bf16(Af, Bf[n][kc], acc[n], 0, 0, 0);
    }

    // ---- cross-wave K reduction (lgkm-only barrier)
#pragma unroll
    for (int n = 0; n < 4; ++n)
#pragma unroll
      for (int r = 0; r < 4; ++r)
        pbuf[w][lgq * 4 + r][n * 16 + lrow] = acc[n][r];
    asm volatile("s_waitcnt lgkmcnt(0)\ns_barrier" ::: "memory");
    __builtin_amdgcn_sched_barrier(0);

    // ---- pointwise: vectorized partial-sum + leaky update + relu
    f4_t s0 = *(const f4_t*)&pbuf[0][pr][pc];
    f4_t s1 = *(const f4_t*)&pbuf[1][pr][pc];
    f4_t s2 = *(const f4_t*)&pbuf[2][pr][pc];
    f4_t s3 = *(const f4_t*)&pbuf[3][pr][pc];
    f4_t tot = s0 + s1 + s2 + s3 + ucur + bh4;
    f4_t hres;
#pragma unroll
    for (int j = 0; j < 4; ++j) {
      st[j] = st[j] * 0.8f + tot[j] * 0.2f;
      hres[j] = fmaxf(st[j], 0.f);
    }

    // ---- tagged h store (fire-and-forget; tags self-validate)
    unsigned long long hp = pack4bf(hres) | (((t >> 1) & 1) ? SMASK : 0ull);
    __hip_atomic_store(
        (unsigned long long*)(hb[p] + (size_t)(b0 + pr) * H_DIM + h0 + pc), hp,
        __ATOMIC_RELAXED, __HIP_MEMORY_SCOPE_AGENT);

    asm volatile("s_barrier" ::: "memory");  // stores issued (no ack wait)
    if (tid == 0)
      __hip_atomic_store(myslot, (unsigned)(t + 1), __ATOMIC_RELAXED,
                         __HIP_MEMORY_SCOPE_AGENT);  // hint flag

    *(f4_t*)(act + ((size_t)t * B_DIM + b0 + pr) * H_DIM + h0 + pc) = hres;
    ucur = unext;
  }
}

// ------------------------------------------------- phase 3: act @ Wo^T + bo -
__global__ __launch_bounds__(256, 2) void k_outproj(
    const float* __restrict__ act, const unsigned short* __restrict__ Wo_b,
    const float* __restrict__ bo, float* __restrict__ out) {
  __shared__ unsigned short As[128 * 64];
  __shared__ unsigned short Bs[128 * 64];
  int m0 = blockIdx.x * 128;
  int tid = threadIdx.x;
  int lane = tid & 63, w = tid >> 6;
  int wm0 = (w & 1) * 64, wn0 = (w >> 1) * 64;
  int lrow = lane & 15, lk = (lane >> 4) * 8;
  f4_t acc[4][4];
#pragma unroll
  for (int a = 0; a < 4; ++a)
#pragma unroll
    for (int b = 0; b < 4; ++b) acc[a][b] = (f4_t){0.f, 0.f, 0.f, 0.f};

  for (int kb = 0; kb < 16; ++kb) {
    if (kb) __syncthreads();
#pragma unroll
    for (int it = 0; it < 8; ++it) {
      int c = it * 256 + tid;
      int row = c >> 4;
      int kc = (c & 15) * 4;
      f4_t v = *(const f4_t*)(act + (size_t)(m0 + row) * H_DIM + kb * 64 + kc);
      *(unsigned long long*)((char*)As + SWZ(row, row * 128 + kc * 2)) = pack4bf(v);
    }
#pragma unroll
    for (int it = 0; it < 4; ++it) {
      int c = it * 256 + tid;
      int row = c >> 3;
      int k16 = c & 7;
      u32x4 v = *(const u32x4*)(Wo_b + (size_t)row * H_DIM + kb * 64 + k16 * 8);
      *(u32x4*)((char*)Bs + SWZ(row, row * 128 + k16 * 16)) = v;
    }
    __syncthreads();
#pragma unroll
    for (int ks = 0; ks < 2; ++ks) {
      bf8_t aF[4], bF[4];
#pragma unroll
      for (int mt = 0; mt < 4; ++mt) {
        int row = wm0 + mt * 16 + lrow;
        aF[mt] = *(const bf8_t*)((char*)As + SWZ(row, row * 128 + (ks * 32 + lk) * 2));
      }
#pragma unroll
      for (int nt = 0; nt < 4; ++nt) {
        int row = wn0 + nt * 16 + lrow;
        bF[nt] = *(const bf8_t*)((char*)Bs + SWZ(row, row * 128 + (ks * 32 + lk) * 2));
      }
#pragma unroll
      for (int mt = 0; mt < 4; ++mt)
#pragma unroll
        for (int nt = 0; nt < 4; ++nt)
          acc[mt][nt] =
              __builtin_amdgcn_mfma_f32_16x16x32_bf16(aF[mt], bF[nt], acc[mt][nt], 0, 0, 0);
    }
  }
#pragma unroll
  for (int nt = 0; nt < 4; ++nt) {
    int col = wn0 + nt * 16 + lrow;
    float bv = bo[col];
#pragma unroll
    for (int mt = 0; mt < 4; ++mt) {
      int rbase = m0 + wm0 + mt * 16 + (lane >> 4) * 4;
#pragma unroll
      for (int r = 0; r < 4; ++r)
        out[(size_t)(rbase + r) * O_DIM + col] = acc[mt][nt][r] + bv;
    }
  }
}

// ---------------------------------------------------------------------------
extern "C" void kernel_launch(void* const* d_in, const int* in_sizes, int n_in,
                              void* d_out, int out_size, void* d_ws, size_t ws_size,
                              hipStream_t stream) {
  const float* x  = (const float*)d_in[0];
  const float* Wi = (const float*)d_in[1];
  const float* bi = (const float*)d_in[2];
  const float* Wh = (const float*)d_in[3];
  const float* bh = (const float*)d_in[4];
  const float* Wo = (const float*)d_in[5];
  const float* bo = (const float*)d_in[6];

  float* out = (float*)d_out;                                  // [T,B,O]
  float* act = out + (size_t)T_DIM * B_DIM * O_DIM;            // [T,B,H]

  char* ws = (char*)d_ws;
  unsigned short* Wh_b  = (unsigned short*)(ws);                               // 2 MB
  unsigned short* Wi_b  = (unsigned short*)(ws + (2u << 20));                  // 512 KB
  unsigned short* Wo_b  = (unsigned short*)(ws + (2u << 20) + (512u << 10));   // 256 KB
  unsigned short* hbuf0 = (unsigned short*)(ws + (2u << 20) + (768u << 10));   // 512 KB
  unsigned short* hbuf1 = (unsigned short*)(ws + (2u << 20) + (1280u << 10));  // 512 KB
  unsigned* done        = (unsigned*)(ws + (2u << 20) + (1792u << 10));        // 32 KB

  k_init<<<1024, 256, 0, stream>>>(Wi, Wh, Wo, Wi_b, Wh_b, Wo_b, hbuf1, done);
  k_inproj<<<8192, 256, 0, stream>>>(x, Wi_b, bi, act);
  k_scan<<<256, 256, 0, stream>>>(Wh_b, bh, act, hbuf0, hbuf1, done);
  k_outproj<<<1024, 256, 0, stream>>>(act, Wo_b, bo, out);
}